// Round 16
// baseline (123.736 us; speedup 1.0000x reference)
//
#include <hip/hip_runtime.h>

#define CS   224
#define HH   1024
#define WW   1024
#define HW   (HH * WW)
#define RT   16              // rows per column tile
#define NTIL (HH / RT)       // 64
#define NCOLG 2              // 1024 cols / (256 threads * 2 floats)
#define RWS  8               // output rows per gather block

typedef float f4u __attribute__((ext_vector_type(4), aligned(4)));
typedef float f2u __attribute__((ext_vector_type(2), aligned(4)));
typedef float f2s __attribute__((ext_vector_type(2), aligned(8)));

// ---- Pass 1: per-row inclusive cumsum into I (3072 blocks) -----------------
__global__ __launch_bounds__(256) void row_cumsum(
    const float* __restrict__ x, float* __restrict__ I)
{
    int row = blockIdx.x;                       // 0 .. 3*1024-1
    const float4* src = (const float4*)(x + (size_t)row * WW);
    float4*       dst = (float4*)(I + (size_t)row * WW);

    int t    = threadIdx.x;
    int lane = t & 63;
    int w    = t >> 6;

    float4 v = src[t];
    float s0 = v.x, s1 = s0 + v.y, s2 = s1 + v.z, s3 = s2 + v.w;
    float tsum = s3, sc = tsum;
    #pragma unroll
    for (int d = 1; d < 64; d <<= 1) {
        float o = __shfl_up(sc, d, 64);
        if (lane >= d) sc += o;
    }

    __shared__ float wsum[4];
    if (lane == 63) wsum[w] = sc;
    __syncthreads();
    float woff = 0.0f;
    #pragma unroll
    for (int k = 0; k < 4; ++k) woff += (k < w) ? wsum[k] : 0.0f;

    float ex = woff + sc - tsum;
    dst[t] = make_float4(ex + s0, ex + s1, ex + s2, ex + s3);
}

// ---- Pass 2: read-only tile column sums -> S -------------------------------
__global__ __launch_bounds__(256) void col_sum(
    const float* __restrict__ I, float* __restrict__ Sf)
{
    int b    = blockIdx.x;
    int tile = b % NTIL;
    int cg   = (b / NTIL) % NCOLG;
    int ch   = b / (NTIL * NCOLG);
    int c2   = cg * 256 + threadIdx.x;

    const float2* base = (const float2*)(I + (size_t)ch * HW
                                           + (size_t)(tile * RT) * WW) + c2;
    float2 acc = make_float2(0.0f, 0.0f);
    #pragma unroll
    for (int r = 0; r < RT; ++r) {
        float2 v = base[(size_t)r * (WW / 2)];
        acc.x += v.x; acc.y += v.y;
    }
    ((float2*)Sf)[(size_t)(ch * NTIL + tile) * (WW / 2) + c2] = acc;
}

// ---- Pass 3: inclusive scan of the 64 tile sums per column (wave/column) ---
__global__ __launch_bounds__(256) void scan_S(float* __restrict__ Sf)
{
    int gw   = (blockIdx.x * 256 + threadIdx.x) >> 6;   // global wave id
    int lane = threadIdx.x & 63;
    int c    = gw % WW;
    int ch   = gw / WW;

    size_t idx = ((size_t)(ch * NTIL + lane)) * WW + c;
    float v = Sf[idx];
    #pragma unroll
    for (int d = 1; d < 64; d <<= 1) {
        float o = __shfl_up(v, d, 64);
        if (lane >= d) v += o;
    }
    Sf[idx] = v;
}

// ---- Pass 4: fused within-tile cumsum + scanned offset (one I pass) --------
__global__ __launch_bounds__(256) void col_apply(
    float* __restrict__ I, const float* __restrict__ Sf)
{
    int b    = blockIdx.x;
    int tile = b % NTIL;
    int cg   = (b / NTIL) % NCOLG;
    int ch   = b / (NTIL * NCOLG);
    int c2   = cg * 256 + threadIdx.x;

    float2 acc = make_float2(0.0f, 0.0f);
    if (tile > 0)
        acc = ((const float2*)Sf)[(size_t)(ch * NTIL + tile - 1) * (WW / 2) + c2];

    float2* base = (float2*)(I + (size_t)ch * HW + (size_t)(tile * RT) * WW) + c2;
    #pragma unroll
    for (int r = 0; r < RT; ++r) {
        float2 v = base[(size_t)r * (WW / 2)];
        acc.x += v.x; acc.y += v.y;
        base[(size_t)r * (WW / 2)] = acc;
    }
}

// ---- window load + static-index selects (K0 = floor(s/224), block-uniform) -
template<int K0>
__device__ __forceinline__ void ldwin(const float* __restrict__ p, float v[12])
{
    f4u q0 = *(const f4u*)p;
    v[0] = q0.x; v[1] = q0.y; v[2] = q0.z; v[3] = q0.w;
    if constexpr (K0 == 1) {
        f2u e = *(const f2u*)(p + 4);
        v[4] = e.x; v[5] = e.y;
    } else if constexpr (K0 == 2) {
        f4u q1 = *(const f4u*)(p + 4);
        v[4] = q1.x; v[5] = q1.y; v[6] = q1.z; v[7] = q1.w;
    } else if constexpr (K0 == 3) {
        f4u q1 = *(const f4u*)(p + 4);
        v[4] = q1.x; v[5] = q1.y; v[6] = q1.z; v[7] = q1.w;
        f2u e = *(const f2u*)(p + 8);
        v[8] = e.x; v[9] = e.y;
    } else {
        f4u q1 = *(const f4u*)(p + 4);
        v[4] = q1.x; v[5] = q1.y; v[6] = q1.z; v[7] = q1.w;
        f4u q2 = *(const f4u*)(p + 8);
        v[8] = q2.x; v[9] = q2.y; v[10] = q2.z; v[11] = q2.w;
    }
}

template<int K0>
__device__ __forceinline__ float selB0(const float v[12], int nC0) {
    float r = v[K0];
    r = (nC0 == K0 + 1) ? v[K0 + 1] : r;
    r = (nC0 == K0 + 2) ? v[K0 + 2] : r;
    return r;
}
template<int K0>
__device__ __forceinline__ float selA1(const float v[12], int d) {
    return (d == K0) ? v[K0] : v[K0 + 1];
}
template<int K0>
__device__ __forceinline__ float selB1(const float v[12], int db) {
    float r = v[2 * K0];
    r = (db == 2 * K0 + 1) ? v[2 * K0 + 1] : r;
    r = (db == 2 * K0 + 2) ? v[2 * K0 + 2] : r;
    r = (db == 2 * K0 + 3) ? v[2 * K0 + 3] : r;
    return r;
}

template<int K0>
__device__ __forceinline__ void gather_impl(
    const float* __restrict__ Ic, int s, int oy_, int ox_,
    int rg, int p, int ro, float* __restrict__ outrowbase)
{
    int j0 = 2 * p;
    int j1 = j0 + 1;
    int lo0 = (j0 * s) / CS;
    int hi0 = ((j0 + 1) * s + CS - 1) / CS;
    int lo1 = (j1 * s) / CS;
    int hi1 = ((j1 + 1) * s + CS - 1) / CS;
    int nC0 = hi0 - lo0;
    int nC1 = hi1 - lo1;
    int d   = lo1 - lo0;
    int db  = d + nC1;
    int acol = ox_ + lo0 - 1;              // may be -1 (I has 16B front pad)
    bool am0 = (ox_ + lo0) > 0;
    float rC0 = __builtin_amdgcn_rcpf((float)nC0);
    float rC1 = __builtin_amdgcn_rcpf((float)nC1);

    #pragma unroll
    for (int rr = 0; rr < RWS / 2; ++rr) {
        int i    = rg * RWS + ro + 2 * rr;
        int lo_i = (i * s) / CS;
        int nR   = ((i + 1) * s + CS - 1) / CS - lo_i;
        int r0   = oy_ + lo_i;
        int r1m  = r0 + nR - 1;
        bool rm  = (r0 > 0);
        int r0m  = rm ? (r0 - 1) : 0;

        float vh[12], vl[12];
        ldwin<K0>(Ic + (size_t)r1m * WW + acol, vh);
        ldwin<K0>(Ic + (size_t)r0m * WW + acol, vl);

        float ah0 = vh[0],            al0 = vl[0];
        float bh0 = selB0<K0>(vh, nC0), bl0 = selB0<K0>(vl, nC0);
        float ah1 = selA1<K0>(vh, d),   al1 = selA1<K0>(vl, d);
        float bh1 = selB1<K0>(vh, db),  bl1 = selB1<K0>(vl, db);

        float s0 = (bh0 - (am0 ? ah0 : 0.0f))
                 - (rm ? (bl0 - (am0 ? al0 : 0.0f)) : 0.0f);
        float s1 = (bh1 - ah1) - (rm ? (bl1 - al1) : 0.0f);

        float rR = __builtin_amdgcn_rcpf((float)nR);
        f2s st;
        st.x = s0 * (rC0 * rR);
        st.y = s1 * (rC1 * rR);
        *(f2s*)(outrowbase + (size_t)i * CS + j0) = st;
    }
}

// ---- Pass 5: gather. Block = 8 rows of one (n,ch); lane = 2 columns. -------
__global__ __launch_bounds__(256) void cutouts_gather(
    const float* __restrict__ I,
    const int*   __restrict__ sizesv,
    const int*   __restrict__ oyv,
    const int*   __restrict__ oxv,
    float*       __restrict__ out)
{
    int b   = blockIdx.x;              // ((ch*128)+n)*28 + rg
    int rg  = b % (CS / RWS);
    int rem = b / (CS / RWS);
    int n   = rem % 128;
    int ch  = rem / 128;               // slowest: working set = one 4MB plane

    int tid = threadIdx.x;
    int p   = tid & 127;               // column pair index
    int ro  = tid >> 7;                // row parity (wave-uniform)
    if (p >= 112) return;

    int s   = sizesv[n];               // block-uniform -> scalar
    int oy_ = oyv[n];
    int ox_ = oxv[n];

    const float* Ic = I + (size_t)ch * HW;
    float* outrowbase = out + (size_t)((n * 3 + ch) * CS) * CS;

    int k0 = s / CS;                   // 1..4, block-uniform
    if      (k0 == 1) gather_impl<1>(Ic, s, oy_, ox_, rg, p, ro, outrowbase);
    else if (k0 == 2) gather_impl<2>(Ic, s, oy_, ox_, rg, p, ro, outrowbase);
    else if (k0 == 3) gather_impl<3>(Ic, s, oy_, ox_, rg, p, ro, outrowbase);
    else              gather_impl<4>(Ic, s, oy_, ox_, rg, p, ro, outrowbase);
}

extern "C" void kernel_launch(void* const* d_in, const int* in_sizes, int n_in,
                              void* d_out, int out_size, void* d_ws, size_t ws_size,
                              hipStream_t stream) {
    const float* x     = (const float*)d_in[0];
    const int*   sizes = (const int*)d_in[1];
    const int*   oy    = (const int*)d_in[2];
    const int*   ox    = (const int*)d_in[3];
    float*       out   = (float*)d_out;

    // I sits 16 B into d_ws so the acol = -1 window read stays in-bounds;
    // right-edge over-reads (<= 44 B past I) also stay inside d_ws
    // (ws_size >= 24 MB, proven by R13's main path having run).
    float* I = (float*)((char*)d_ws + 16);

    // Tile sums S (3*64*1024 floats = 768 KB) in the tail of d_out;
    // fully consumed by col_apply before the gather overwrites all of d_out.
    float* S = out + (out_size - 3 * NTIL * WW);

    row_cumsum<<<3 * HH, 256, 0, stream>>>(x, I);
    col_sum<<<3 * NCOLG * NTIL, 256, 0, stream>>>(I, S);
    scan_S<<<(3 * WW) / 4, 256, 0, stream>>>(S);       // 768 blocks
    col_apply<<<3 * NCOLG * NTIL, 256, 0, stream>>>(I, S);

    int blocks = 3 * 128 * (CS / RWS);                // 10752
    cutouts_gather<<<blocks, 256, 0, stream>>>(I, sizes, oy, ox, out);
}

// Round 17
// 67.921 us; speedup vs baseline: 1.8218x; 1.8218x over previous
//
#include <hip/hip_runtime.h>

#define CS   224
#define HH   1024
#define WW   1024
#define HW   (HH * WW)
#define RT   16              // rows per column tile
#define NTIL (HH / RT)       // 64
#define NCOLG 2              // 1024 cols / (256 threads * 2 floats)
#define RWS  8               // output rows per gather block

typedef float f2u __attribute__((ext_vector_type(2), aligned(4)));
typedef float f2s __attribute__((ext_vector_type(2), aligned(8)));

// ---- Pass 1: per-row inclusive cumsum into I (3072 blocks) -----------------
__global__ __launch_bounds__(256) void row_cumsum(
    const float* __restrict__ x, float* __restrict__ I)
{
    int row = blockIdx.x;                       // 0 .. 3*1024-1
    const float4* src = (const float4*)(x + (size_t)row * WW);
    float4*       dst = (float4*)(I + (size_t)row * WW);

    int t    = threadIdx.x;
    int lane = t & 63;
    int w    = t >> 6;

    float4 v = src[t];
    float s0 = v.x, s1 = s0 + v.y, s2 = s1 + v.z, s3 = s2 + v.w;
    float tsum = s3, sc = tsum;
    #pragma unroll
    for (int d = 1; d < 64; d <<= 1) {
        float o = __shfl_up(sc, d, 64);
        if (lane >= d) sc += o;
    }

    __shared__ float wsum[4];
    if (lane == 63) wsum[w] = sc;
    __syncthreads();
    float woff = 0.0f;
    #pragma unroll
    for (int k = 0; k < 4; ++k) woff += (k < w) ? wsum[k] : 0.0f;

    float ex = woff + sc - tsum;
    dst[t] = make_float4(ex + s0, ex + s1, ex + s2, ex + s3);
}

// ---- Pass 2: read-only tile column sums -> S -------------------------------
__global__ __launch_bounds__(256) void col_sum(
    const float* __restrict__ I, float* __restrict__ Sf)
{
    int b    = blockIdx.x;
    int tile = b % NTIL;
    int cg   = (b / NTIL) % NCOLG;
    int ch   = b / (NTIL * NCOLG);
    int c2   = cg * 256 + threadIdx.x;

    const float2* base = (const float2*)(I + (size_t)ch * HW
                                           + (size_t)(tile * RT) * WW) + c2;
    float2 acc = make_float2(0.0f, 0.0f);
    #pragma unroll
    for (int r = 0; r < RT; ++r) {
        float2 v = base[(size_t)r * (WW / 2)];
        acc.x += v.x; acc.y += v.y;
    }
    ((float2*)Sf)[(size_t)(ch * NTIL + tile) * (WW / 2) + c2] = acc;
}

// ---- Pass 3: inclusive scan of the 64 tile sums per column (wave/column) ---
__global__ __launch_bounds__(256) void scan_S(float* __restrict__ Sf)
{
    int gw   = (blockIdx.x * 256 + threadIdx.x) >> 6;   // global wave id
    int lane = threadIdx.x & 63;
    int c    = gw % WW;
    int ch   = gw / WW;

    size_t idx = ((size_t)(ch * NTIL + lane)) * WW + c;
    float v = Sf[idx];
    #pragma unroll
    for (int d = 1; d < 64; d <<= 1) {
        float o = __shfl_up(v, d, 64);
        if (lane >= d) v += o;
    }
    Sf[idx] = v;
}

// ---- Pass 4: fused within-tile cumsum + scanned offset (one I pass) --------
__global__ __launch_bounds__(256) void col_apply(
    float* __restrict__ I, const float* __restrict__ Sf)
{
    int b    = blockIdx.x;
    int tile = b % NTIL;
    int cg   = (b / NTIL) % NCOLG;
    int ch   = b / (NTIL * NCOLG);
    int c2   = cg * 256 + threadIdx.x;

    float2 acc = make_float2(0.0f, 0.0f);
    if (tile > 0)
        acc = ((const float2*)Sf)[(size_t)(ch * NTIL + tile - 1) * (WW / 2) + c2];

    float2* base = (float2*)(I + (size_t)ch * HW + (size_t)(tile * RT) * WW) + c2;
    #pragma unroll
    for (int r = 0; r < RT; ++r) {
        float2 v = base[(size_t)r * (WW / 2)];
        acc.x += v.x; acc.y += v.y;
        base[(size_t)r * (WW / 2)] = acc;
    }
}

// ---- Pass 5: gather. Block = 8 rows of one (n,ch); thread = 2 cols x 4 rows.
// Pair structure: bcol0 - acol1 = hi0 - lo1 in {0,1}, so a dwordx2 at acol1
// provides BOTH the j1 a-tap (elem 0) and the j0 b-tap (elem selb0).
// 3 loads per SAT-row level per 2 outputs; dwordx2 stores. No arrays
// (everything named scalars -> no alloca-to-LDS promotion).
__global__ __launch_bounds__(256) void cutouts_gather(
    const float* __restrict__ I,
    const int*   __restrict__ sizesv,
    const int*   __restrict__ oyv,
    const int*   __restrict__ oxv,
    float*       __restrict__ out)
{
    int b   = blockIdx.x;              // ((ch*128)+n)*28 + rg
    int rg  = b % (CS / RWS);
    int rem = b / (CS / RWS);
    int n   = rem % 128;
    int ch  = rem / 128;               // slowest: working set = one 4MB plane

    int tid = threadIdx.x;
    int p   = tid & 127;               // column-pair index
    int ro  = tid >> 7;                // which 4-row half (wave-uniform)
    if (p >= 112) return;

    int s   = sizesv[n];               // block-uniform -> scalar
    int oy_ = oyv[n];
    int ox_ = oxv[n];

    // per-lane column math (once for 4 rows)
    int j0  = 2 * p, j1 = j0 + 1;
    int lo0 = (j0 * s) / CS;
    int hi0 = ((j0 + 1) * s + CS - 1) / CS;
    int lo1 = (j1 * s) / CS;
    int hi1 = ((j1 + 1) * s + CS - 1) / CS;
    int acol0 = ox_ + lo0 - 1;         // may be -1: I has 16B front pad
    int acol1 = ox_ + lo1 - 1;         // >= 0 always (lo1 >= 1)
    int bcol1 = ox_ + hi1 - 1;
    bool sb0  = (hi0 - lo1) != 0;      // bcol0 = acol1 + (0|1)
    bool am0  = (ox_ + lo0) > 0;
    float rC0 = __builtin_amdgcn_rcpf((float)(hi0 - lo0));
    float rC1 = __builtin_amdgcn_rcpf((float)(hi1 - lo1));

    const float* Ic = I + (size_t)ch * HW;
    float* ob = out + (size_t)((n * 3 + ch) * CS) * CS;

    #pragma unroll
    for (int rr = 0; rr < RWS / 2; ++rr) {
        int i    = rg * RWS + ro * (RWS / 2) + rr;
        int lo_i = (i * s) / CS;
        int nR   = ((i + 1) * s + CS - 1) / CS - lo_i;
        int r0   = oy_ + lo_i;
        int r1m  = r0 + nR - 1;
        bool rm  = (r0 > 0);
        int r0m  = rm ? (r0 - 1) : 0;

        const float* Rhi = Ic + (size_t)r1m * WW;
        const float* Rlo = Ic + (size_t)r0m * WW;

        float ah0 = Rhi[acol0];
        f2u   mh  = *(const f2u*)(Rhi + acol1);
        float bh1 = Rhi[bcol1];
        float al0 = Rlo[acol0];
        f2u   ml  = *(const f2u*)(Rlo + acol1);
        float bl1 = Rlo[bcol1];

        float bh0 = sb0 ? mh.y : mh.x;
        float ah1 = mh.x;
        float bl0 = sb0 ? ml.y : ml.x;
        float al1 = ml.x;

        float s0 = (bh0 - (am0 ? ah0 : 0.0f))
                 - (rm ? (bl0 - (am0 ? al0 : 0.0f)) : 0.0f);
        float s1 = (bh1 - ah1) - (rm ? (bl1 - al1) : 0.0f);

        float rR = __builtin_amdgcn_rcpf((float)nR);
        f2s st;
        st.x = s0 * (rC0 * rR);
        st.y = s1 * (rC1 * rR);
        *(f2s*)(ob + (size_t)i * CS + j0) = st;
    }
}

extern "C" void kernel_launch(void* const* d_in, const int* in_sizes, int n_in,
                              void* d_out, int out_size, void* d_ws, size_t ws_size,
                              hipStream_t stream) {
    const float* x     = (const float*)d_in[0];
    const int*   sizes = (const int*)d_in[1];
    const int*   oy    = (const int*)d_in[2];
    const int*   ox    = (const int*)d_in[3];
    float*       out   = (float*)d_out;

    // I sits 16 B into d_ws so the acol0 = -1 scalar read stays in-bounds
    // (value is masked by am0; only the address must be legal).
    float* I = (float*)((char*)d_ws + 16);

    // Tile sums S (3*64*1024 floats = 768 KB) in the tail of d_out;
    // fully consumed by col_apply before the gather overwrites all of d_out.
    float* S = out + (out_size - 3 * NTIL * WW);

    row_cumsum<<<3 * HH, 256, 0, stream>>>(x, I);
    col_sum<<<3 * NCOLG * NTIL, 256, 0, stream>>>(I, S);
    scan_S<<<(3 * WW) / 4, 256, 0, stream>>>(S);       // 768 blocks
    col_apply<<<3 * NCOLG * NTIL, 256, 0, stream>>>(I, S);

    int blocks = 3 * 128 * (CS / RWS);                // 10752
    cutouts_gather<<<blocks, 256, 0, stream>>>(I, sizes, oy, ox, out);
}